// Round 2
// baseline (8023.523 us; speedup 1.0000x reference)
//
#include <hip/hip_runtime.h>
#include <math.h>

#define EPS_LN 1e-5f
#define CLAMP_V 1e-4f
#define TOPK 32
#define BM 16
#define BK 64

// ---------- K1: per-row mean / rsqrt(var) ----------
__global__ void row_stats_kernel(const float* __restrict__ x,
                                 float* __restrict__ mu_out,
                                 float* __restrict__ rs_out,
                                 int nrows, int D) {
  const int wave = threadIdx.x >> 6;
  const int lane = threadIdx.x & 63;
  const int row = blockIdx.x * 4 + wave;
  if (row >= nrows) return;
  const float4* p = (const float4*)(x + (size_t)row * D);
  const int nv = D >> 2;
  float s0 = 0.f, s2 = 0.f;
  for (int i = lane; i < nv; i += 64) {
    float4 v = p[i];
    s0 += v.x + v.y + v.z + v.w;
    s2 += v.x * v.x + v.y * v.y + v.z * v.z + v.w * v.w;
  }
  #pragma unroll
  for (int off = 32; off; off >>= 1) {
    s0 += __shfl_xor(s0, off);
    s2 += __shfl_xor(s2, off);
  }
  if (lane == 0) {
    float mu = s0 / (float)D;
    float var = s2 / (float)D - mu * mu;
    mu_out[row] = mu;
    rs_out[row] = rsqrtf(var + EPS_LN);
  }
}

__device__ __forceinline__ float block_sum4(float v, float* red, int tid) {
  #pragma unroll
  for (int off = 32; off; off >>= 1) v += __shfl_xor(v, off);
  if ((tid & 63) == 0) red[tid >> 6] = v;
  __syncthreads();
  float s = red[0] + red[1] + red[2] + red[3];
  __syncthreads();
  return s;
}

// ---------- K2: q_proj = LN2(LN1(q)@qW + qb); emit wq = r_g2*qp, c1, c2 ----------
__global__ void qproj_kernel(const float* __restrict__ q,
                             const float* __restrict__ qg1, const float* __restrict__ qb1,
                             const float* __restrict__ qW,  const float* __restrict__ qb,
                             const float* __restrict__ qg2, const float* __restrict__ qb2,
                             const float* __restrict__ rg2, const float* __restrict__ rb2,
                             float* __restrict__ wq, float* __restrict__ c12,
                             int D, int H) {
  __shared__ float xs[2048];
  __shared__ float red[4];
  const int b = blockIdx.x;
  const int tid = threadIdx.x;  // 256
  const float* qrow = q + (size_t)b * D;
  float s0 = 0.f, s2 = 0.f;
  for (int i = tid; i < (D >> 2); i += 256) {
    float4 v = ((const float4*)qrow)[i];
    s0 += v.x + v.y + v.z + v.w;
    s2 += v.x * v.x + v.y * v.y + v.z * v.z + v.w * v.w;
  }
  s0 = block_sum4(s0, red, tid);
  s2 = block_sum4(s2, red, tid);
  const float mu = s0 / (float)D;
  const float rs = rsqrtf(s2 / (float)D - mu * mu + EPS_LN);
  for (int i = tid; i < D; i += 256)
    xs[i] = (qrow[i] - mu) * rs * qg1[i] + qb1[i];
  __syncthreads();
  // y[h], h = tid + 256*j  (H assumed = 1024)
  float y[4];
  #pragma unroll
  for (int j = 0; j < 4; ++j) y[j] = qb[tid + (j << 8)];
  for (int d = 0; d < D; ++d) {
    const float xv = xs[d];
    const float* wrow = qW + (size_t)d * H + tid;
    #pragma unroll
    for (int j = 0; j < 4; ++j) y[j] += xv * wrow[j << 8];
  }
  float t0 = 0.f, t2 = 0.f;
  #pragma unroll
  for (int j = 0; j < 4; ++j) { t0 += y[j]; t2 += y[j] * y[j]; }
  t0 = block_sum4(t0, red, tid);
  t2 = block_sum4(t2, red, tid);
  const float mu2 = t0 / (float)H;
  const float rs2 = rsqrtf(t2 / (float)H - mu2 * mu2 + EPS_LN);
  float pc1 = 0.f, pc2 = 0.f;
  #pragma unroll
  for (int j = 0; j < 4; ++j) {
    const int h = tid + (j << 8);
    const float qp = (y[j] - mu2) * rs2 * qg2[h] + qb2[h];
    const float wv = rg2[h] * qp;
    wq[(size_t)b * H + h] = wv;
    pc1 += wv;
    pc2 += rb2[h] * qp;
  }
  pc1 = block_sum4(pc1, red, tid);
  pc2 = block_sum4(pc2, red, tid);
  if (tid == 0) { c12[2 * b] = pc1; c12[2 * b + 1] = pc2; }
}

// ---------- K3: fused [rows x D] @ [D x H] + LN2 + score-dot ----------
__launch_bounds__(256, 3)
__global__ void rproj_score_kernel(const float* __restrict__ r,
                                   const float* __restrict__ mu_r, const float* __restrict__ rs_r,
                                   const float* __restrict__ rg1, const float* __restrict__ rb1,
                                   const float* __restrict__ rW,  const float* __restrict__ rbias,
                                   const float* __restrict__ wq,  const float* __restrict__ c12,
                                   float* __restrict__ scores,
                                   int N, int D, int H, float inv_sqrt_h) {
  __shared__ float a_sh[BM][BK + 4];
  __shared__ float part[4][8][4];
  const int tid = threadIdx.x;       // 256
  const int row0 = blockIdx.x * BM;
  const int b = row0 / N;
  const int rgrp = tid >> 7;         // 0..1 : owns rows rgrp*8 .. rgrp*8+7
  const int hgrp = tid & 127;        // h = hgrp*8 + j
  const int srow = tid >> 4;         // staging row 0..15
  const int skk  = (tid & 15) << 2;  // staging k offset
  const float smu = mu_r[row0 + srow];
  const float srs = rs_r[row0 + srow];

  float acc[8][8];
  #pragma unroll
  for (int i = 0; i < 8; ++i)
    #pragma unroll
    for (int j = 0; j < 8; ++j) acc[i][j] = 0.f;

  for (int kt = 0; kt < D; kt += BK) {
    __syncthreads();
    {
      const float4 v  = *(const float4*)(r + (size_t)(row0 + srow) * D + kt + skk);
      const float4 g  = *(const float4*)(rg1 + kt + skk);
      const float4 bb = *(const float4*)(rb1 + kt + skk);
      a_sh[srow][skk + 0] = (v.x - smu) * srs * g.x + bb.x;
      a_sh[srow][skk + 1] = (v.y - smu) * srs * g.y + bb.y;
      a_sh[srow][skk + 2] = (v.z - smu) * srs * g.z + bb.z;
      a_sh[srow][skk + 3] = (v.w - smu) * srs * g.w + bb.w;
    }
    __syncthreads();
    const float* wp = rW + (size_t)kt * H + (hgrp << 3);
    #pragma unroll 4
    for (int k4 = 0; k4 < BK; k4 += 4) {
      float4 av[8];
      #pragma unroll
      for (int i = 0; i < 8; ++i)
        av[i] = *(const float4*)&a_sh[(rgrp << 3) + i][k4];
      #pragma unroll
      for (int kk = 0; kk < 4; ++kk) {
        const float* wrow = wp + (size_t)(k4 + kk) * H;
        const float4 w0 = *(const float4*)(wrow);
        const float4 w1 = *(const float4*)(wrow + 4);
        #pragma unroll
        for (int i = 0; i < 8; ++i) {
          const float a = (kk == 0) ? av[i].x : (kk == 1) ? av[i].y
                        : (kk == 2) ? av[i].z : av[i].w;
          acc[i][0] += a * w0.x; acc[i][1] += a * w0.y;
          acc[i][2] += a * w0.z; acc[i][3] += a * w0.w;
          acc[i][4] += a * w1.x; acc[i][5] += a * w1.y;
          acc[i][6] += a * w1.z; acc[i][7] += a * w1.w;
        }
      }
    }
  }
  // epilogue: add bias, per-row reductions S0, S2, S1w
  const float4 rba = *(const float4*)(rbias + (hgrp << 3));
  const float4 rbb = *(const float4*)(rbias + (hgrp << 3) + 4);
  const float4 wqa = *(const float4*)(wq + (size_t)b * H + (hgrp << 3));
  const float4 wqb = *(const float4*)(wq + (size_t)b * H + (hgrp << 3) + 4);
  const float rbv[8] = {rba.x, rba.y, rba.z, rba.w, rbb.x, rbb.y, rbb.z, rbb.w};
  const float wqv[8] = {wqa.x, wqa.y, wqa.z, wqa.w, wqb.x, wqb.y, wqb.z, wqb.w};
  const int wave = tid >> 6;
  const int lane = tid & 63;
  #pragma unroll
  for (int i = 0; i < 8; ++i) {
    float s0 = 0.f, s2 = 0.f, s1 = 0.f;
    #pragma unroll
    for (int j = 0; j < 8; ++j) {
      const float yv = acc[i][j] + rbv[j];
      s0 += yv; s2 += yv * yv; s1 += yv * wqv[j];
    }
    #pragma unroll
    for (int off = 32; off; off >>= 1) {
      s0 += __shfl_xor(s0, off);
      s2 += __shfl_xor(s2, off);
      s1 += __shfl_xor(s1, off);
    }
    if (lane == 0) { part[wave][i][0] = s0; part[wave][i][1] = s2; part[wave][i][2] = s1; }
  }
  __syncthreads();
  if (tid < BM) {
    const int g = tid >> 3;   // which rgrp owns this row -> waves 2g, 2g+1
    const int i = tid & 7;
    const float s0 = part[2*g][i][0] + part[2*g+1][i][0];
    const float s2 = part[2*g][i][1] + part[2*g+1][i][1];
    const float s1 = part[2*g][i][2] + part[2*g+1][i][2];
    const float mu2 = s0 / (float)H;
    const float var = s2 / (float)H - mu2 * mu2;
    const float rs2 = rsqrtf(var + EPS_LN);
    const float c1 = c12[2*b], c2 = c12[2*b+1];
    scores[row0 + tid] = (rs2 * (s1 - mu2 * c1) + c2) * inv_sqrt_h;
  }
}

// ---------- K4: top-k -> softmax -> platt ----------
__global__ void topk_softmax_kernel(const float* __restrict__ scores,
                                    const float* __restrict__ ref_vals,
                                    const float* __restrict__ scale,
                                    const float* __restrict__ res_scale,
                                    const void* __restrict__ tau_raw,
                                    float* __restrict__ out, int N) {
  __shared__ float s_sh[1024];
  __shared__ float tv[TOPK];
  __shared__ int tix[TOPK];
  __shared__ float redv[4];
  __shared__ int redi[4];
  const int b = blockIdx.x;
  const int tid = threadIdx.x;  // 256
  const int wave = tid >> 6, lane = tid & 63;
  for (int i = tid; i < N; i += 256) s_sh[i] = scores[(size_t)b * N + i];
  __syncthreads();
  for (int sel = 0; sel < TOPK; ++sel) {
    float best = -INFINITY; int bi = N;
    for (int i = tid; i < N; i += 256) {
      const float v = s_sh[i];
      if (v > best || (v == best && i < bi)) { best = v; bi = i; }
    }
    #pragma unroll
    for (int off = 32; off; off >>= 1) {
      const float ov = __shfl_xor(best, off);
      const int oi = __shfl_xor(bi, off);
      if (ov > best || (ov == best && oi < bi)) { best = ov; bi = oi; }
    }
    if (lane == 0) { redv[wave] = best; redi[wave] = bi; }
    __syncthreads();
    if (tid == 0) {
      float bv = redv[0]; int bj = redi[0];
      for (int w = 1; w < 4; ++w)
        if (redv[w] > bv || (redv[w] == bv && redi[w] < bj)) { bv = redv[w]; bj = redi[w]; }
      tv[sel] = bv; tix[sel] = bj; s_sh[bj] = -INFINITY;
    }
    __syncthreads();
  }
  if (tid < TOPK) {
    const int ti = *(const int*)tau_raw;
    const float tau = (ti >= -100000 && ti <= 100000) ? (float)ti : *(const float*)tau_raw;
    const float m = tv[0];
    const float e = expf((tv[tid] - m) / tau);
    const float rv = ref_vals[(size_t)b * N + tix[tid]];
    float Z = e, BV = e * rv;
    #pragma unroll
    for (int off = 16; off; off >>= 1) {
      Z += __shfl_xor(Z, off);
      BV += __shfl_xor(BV, off);
    }
    if (tid == 0) {
      const float base = BV / Z;
      const float p = fminf(fmaxf(base, CLAMP_V), 1.f - CLAMP_V);
      const float logit = logf(p) - log1pf(-p);
      const float xv = scale[0] * logit + res_scale[0];
      out[b] = 1.f / (1.f + expf(-xv));
    }
  }
}

extern "C" void kernel_launch(void* const* d_in, const int* in_sizes, int n_in,
                              void* d_out, int out_size, void* d_ws, size_t ws_size,
                              hipStream_t stream) {
  const float* q   = (const float*)d_in[0];
  const float* r   = (const float*)d_in[1];
  const float* ref = (const float*)d_in[2];
  const float* qg1 = (const float*)d_in[3];
  const float* qb1 = (const float*)d_in[4];
  const float* qW  = (const float*)d_in[5];
  const float* qb  = (const float*)d_in[6];
  const float* qg2 = (const float*)d_in[7];
  const float* qb2 = (const float*)d_in[8];
  const float* rg1 = (const float*)d_in[9];
  const float* rb1 = (const float*)d_in[10];
  const float* rW  = (const float*)d_in[11];
  const float* rb  = (const float*)d_in[12];
  const float* rg2 = (const float*)d_in[13];
  const float* rb2 = (const float*)d_in[14];
  const float* scale = (const float*)d_in[15];
  const float* res_scale = (const float*)d_in[16];
  const void*  tau = d_in[17];

  const int D = in_sizes[3];          // 2048
  const int H = in_sizes[6];          // 1024
  const int B = in_sizes[0] / D;      // 64
  const int N = in_sizes[2] / B;      // 1024
  const int nrows = B * N;            // 65536

  float* ws = (float*)d_ws;
  float* mu_r = ws;
  float* rs_r = mu_r + nrows;
  float* wqv  = rs_r + nrows;
  float* c12  = wqv + (size_t)B * H;
  float* scores = c12 + 2 * B;

  row_stats_kernel<<<(nrows + 3) / 4, 256, 0, stream>>>(r, mu_r, rs_r, nrows, D);
  qproj_kernel<<<B, 256, 0, stream>>>(q, qg1, qb1, qW, qb, qg2, qb2, rg2, rb2,
                                      wqv, c12, D, H);
  rproj_score_kernel<<<nrows / BM, 256, 0, stream>>>(r, mu_r, rs_r, rg1, rb1, rW, rb,
                                                     wqv, c12, scores, N, D, H,
                                                     1.0f / sqrtf((float)H));
  topk_softmax_kernel<<<B, 256, 0, stream>>>(scores, ref, scale, res_scale, tau,
                                             (float*)d_out, N);
  (void)n_in; (void)out_size; (void)ws_size;
}